// Round 1
// baseline (911.196 us; speedup 1.0000x reference)
//
#include <hip/hip_runtime.h>
#include <hip/hip_bf16.h>

// Problem constants
#define BB 32
#define LL 256
#define NN 1024
#define BL 8192         // B*L
#define TOPK 307        // int(1024*0.3)

// ---------------------------------------------------------------------------
// K1: inv_norm[b*N + n] = 1 / max(||x[b,:,n]||, 1e-12)
__global__ __launch_bounds__(256) void k_norms(const float* __restrict__ x,
                                               float* __restrict__ invn) {
    int g = blockIdx.x * 256 + threadIdx.x;   // g = b*N + n
    int b = g >> 10, n = g & (NN - 1);
    const float* p = x + (size_t)b * LL * NN + n;
    float s = 0.f;
#pragma unroll 8
    for (int l = 0; l < LL; ++l) {
        float v = p[(size_t)l * NN];
        s = fmaf(v, v, s);
    }
    invn[g] = 1.0f / fmaxf(sqrtf(s), 1e-12f);
}

// ---------------------------------------------------------------------------
// K2: transpose x [R=8192][C=1024] -> xnT[c][r] (raw) and xs[c][r] (scaled)
__global__ __launch_bounds__(256) void k_transpose_x(const float* __restrict__ x,
                                                     const float* __restrict__ invn,
                                                     float* __restrict__ xnT,
                                                     float* __restrict__ xs) {
    __shared__ float tile[32][33];
    int c0 = blockIdx.x * 32;       // node dim
    int r0 = blockIdx.y * 32;       // b*L dim
    int tx = threadIdx.x, ty = threadIdx.y;   // (32,8)
#pragma unroll
    for (int j = 0; j < 32; j += 8)
        tile[ty + j][tx] = x[(size_t)(r0 + ty + j) * NN + c0 + tx];
    __syncthreads();
    int b = r0 >> 8;                // whole tile in same batch (32 | 256)
#pragma unroll
    for (int j = 0; j < 32; j += 8) {
        int n = c0 + ty + j;
        int r = r0 + tx;
        float v = tile[tx][ty + j];
        xnT[(size_t)n * BL + r] = v;
        xs[(size_t)n * BL + r]  = v * invn[b * NN + n];
    }
}

// ---------------------------------------------------------------------------
// SGEMM NT: C[i][j] = alpha * sum_k A[i][k] * Bt[j][k]
// BM=BN=64, BK=16, 256 threads, 4x4 microtile
__global__ __launch_bounds__(256) void k_sgemm_nt(const float* __restrict__ A,
                                                  const float* __restrict__ Bt,
                                                  float* __restrict__ C,
                                                  int M, int Nc, int K, float alpha) {
    __shared__ float As[16][68];
    __shared__ float Bs[16][68];
    const int i0 = blockIdx.y * 64, j0 = blockIdx.x * 64;
    const int t = threadIdx.x;
    const int tx = t & 15, ty = t >> 4;
    const int lr = t >> 2, lc = (t & 3) << 2;
    float acc[4][4] = {};
    const float* Ap = A  + (size_t)(i0 + lr) * K + lc;
    const float* Bp = Bt + (size_t)(j0 + lr) * K + lc;
    for (int k0 = 0; k0 < K; k0 += 16) {
        float4 av = *(const float4*)(Ap + k0);
        float4 bv = *(const float4*)(Bp + k0);
        As[lc + 0][lr] = av.x; As[lc + 1][lr] = av.y;
        As[lc + 2][lr] = av.z; As[lc + 3][lr] = av.w;
        Bs[lc + 0][lr] = bv.x; Bs[lc + 1][lr] = bv.y;
        Bs[lc + 2][lr] = bv.z; Bs[lc + 3][lr] = bv.w;
        __syncthreads();
#pragma unroll
        for (int kk = 0; kk < 16; ++kk) {
            float4 a4 = *(const float4*)&As[kk][ty << 2];
            float4 b4 = *(const float4*)&Bs[kk][tx << 2];
            float a[4] = {a4.x, a4.y, a4.z, a4.w};
            float b[4] = {b4.x, b4.y, b4.z, b4.w};
#pragma unroll
            for (int u = 0; u < 4; ++u)
#pragma unroll
                for (int v = 0; v < 4; ++v)
                    acc[u][v] = fmaf(a[u], b[v], acc[u][v]);
        }
        __syncthreads();
    }
    float* Cp = C + (size_t)(i0 + (ty << 2)) * Nc + j0 + (tx << 2);
#pragma unroll
    for (int u = 0; u < 4; ++u) {
        float4 o;
        o.x = acc[u][0] * alpha; o.y = acc[u][1] * alpha;
        o.z = acc[u][2] * alpha; o.w = acc[u][3] * alpha;
        *(float4*)(Cp + (size_t)u * Nc) = o;
    }
}

// ---------------------------------------------------------------------------
// SGEMM NN: C[i][j] = alpha * sum_k A[i][k] * B[k][j]
__global__ __launch_bounds__(256) void k_sgemm_nn(const float* __restrict__ A,
                                                  const float* __restrict__ Bm,
                                                  float* __restrict__ C,
                                                  int M, int Nc, int K, float alpha) {
    __shared__ float As[16][68];
    __shared__ float Bs[16][68];
    const int i0 = blockIdx.y * 64, j0 = blockIdx.x * 64;
    const int t = threadIdx.x;
    const int tx = t & 15, ty = t >> 4;
    const int lr = t >> 2, lc = (t & 3) << 2;   // A tile: 64 rows x 16 k
    const int bk = t >> 4, bc = (t & 15) << 2;  // B tile: 16 k x 64 cols
    float acc[4][4] = {};
    const float* Ap = A  + (size_t)(i0 + lr) * K + lc;
    const float* Bp = Bm + (size_t)bk * Nc + j0 + bc;
    for (int k0 = 0; k0 < K; k0 += 16) {
        float4 av = *(const float4*)(Ap + k0);
        float4 bv = *(const float4*)(Bp + (size_t)k0 * Nc);
        As[lc + 0][lr] = av.x; As[lc + 1][lr] = av.y;
        As[lc + 2][lr] = av.z; As[lc + 3][lr] = av.w;
        *(float4*)&Bs[bk][bc] = bv;
        __syncthreads();
#pragma unroll
        for (int kk = 0; kk < 16; ++kk) {
            float4 a4 = *(const float4*)&As[kk][ty << 2];
            float4 b4 = *(const float4*)&Bs[kk][tx << 2];
            float a[4] = {a4.x, a4.y, a4.z, a4.w};
            float b[4] = {b4.x, b4.y, b4.z, b4.w};
#pragma unroll
            for (int u = 0; u < 4; ++u)
#pragma unroll
                for (int v = 0; v < 4; ++v)
                    acc[u][v] = fmaf(a[u], b[v], acc[u][v]);
        }
        __syncthreads();
    }
    float* Cp = C + (size_t)(i0 + (ty << 2)) * Nc + j0 + (tx << 2);
#pragma unroll
    for (int u = 0; u < 4; ++u) {
        float4 o;
        o.x = acc[u][0] * alpha; o.y = acc[u][1] * alpha;
        o.z = acc[u][2] * alpha; o.w = acc[u][3] * alpha;
        *(float4*)(Cp + (size_t)u * Nc) = o;
    }
}

// ---------------------------------------------------------------------------
// K3: per-row exact top-307 (excluding self) via radix select on ordered keys.
// A[n][m] = sim[n][m] if kept else 0.  Tie-break: smallest index first.
__global__ __launch_bounds__(256) void k_topk(const float* __restrict__ sim,
                                              float* __restrict__ A) {
    __shared__ unsigned int key[NN];
    __shared__ unsigned int hist[256];
    __shared__ unsigned int s_prefix;
    __shared__ int s_rem;
    const int n = blockIdx.x;
    const int t = threadIdx.x;
    const float* row = sim + (size_t)n * NN;
#pragma unroll
    for (int m = t; m < NN; m += 256) {
        unsigned int u = __float_as_uint(row[m]);
        unsigned int kk = (u & 0x80000000u) ? ~u : (u | 0x80000000u);
        if (m == n) kk = 0u;    // exclude self (self-sim = 1.0 is always max)
        key[m] = kk;
    }
    if (t == 0) { s_rem = TOPK; s_prefix = 0u; }
    __syncthreads();
    unsigned int prefix = 0u;
    for (int pass = 0; pass < 4; ++pass) {
        const int shift = 24 - 8 * pass;
        hist[t] = 0u;
        __syncthreads();
        unsigned int himask = (pass == 0) ? 0u : (0xFFFFFFFFu << (shift + 8));
#pragma unroll
        for (int m = t; m < NN; m += 256) {
            unsigned int kk = key[m];
            if (((kk ^ prefix) & himask) == 0u)
                atomicAdd(&hist[(kk >> shift) & 255u], 1u);
        }
        __syncthreads();
        if (t == 0) {
            int rem = s_rem;
            int b;
            for (b = 255; b > 0; --b) {
                int c = (int)hist[b];
                if (rem <= c) break;
                rem -= c;
            }
            s_rem = rem;
            s_prefix = prefix | ((unsigned int)b << shift);
        }
        __syncthreads();
        prefix = s_prefix;
    }
    const unsigned int T = prefix;
    const int need = s_rem;
    const int cnt_eq = (int)hist[T & 255u];  // exact count of keys == T (last pass)
    if (cnt_eq != need) {
        // rare tie path: keep only first `need` equals by ascending index
        if (t == 0) {
            int c = 0;
            for (int m = 0; m < NN; ++m) {
                if (key[m] == T) {
                    ++c;
                    if (c > need) key[m] = 0u;
                }
            }
        }
        __syncthreads();
    }
#pragma unroll
    for (int m = t; m < NN; m += 256)
        A[(size_t)n * NN + m] = (key[m] >= T) ? row[m] : 0.0f;
}

// ---------------------------------------------------------------------------
// K4: dinv[d] = deg>0 ? 1/sqrt(deg) : 0, deg[d] = sum_s A[s][d]
__global__ __launch_bounds__(256) void k_deg(const float* __restrict__ A,
                                             float* __restrict__ dinv) {
    int d = blockIdx.x * 256 + threadIdx.x;
    float s = 0.f;
#pragma unroll 8
    for (int src = 0; src < NN; ++src) s += A[(size_t)src * NN + d];
    dinv[d] = (s > 0.f) ? (1.0f / sqrtf(s)) : 0.0f;
}

// ---------------------------------------------------------------------------
// K5: Atr[d][s] = A[s][d] * dinv[d] * dinv[s]   (transpose + sym prescale)
__global__ __launch_bounds__(256) void k_prescale_tr(const float* __restrict__ A,
                                                     const float* __restrict__ dinv,
                                                     float* __restrict__ Atr) {
    __shared__ float tile[32][33];
    int c0 = blockIdx.x * 32;   // d
    int r0 = blockIdx.y * 32;   // s
    int tx = threadIdx.x, ty = threadIdx.y;
#pragma unroll
    for (int j = 0; j < 32; j += 8)
        tile[ty + j][tx] = A[(size_t)(r0 + ty + j) * NN + c0 + tx];
    __syncthreads();
#pragma unroll
    for (int j = 0; j < 32; j += 8) {
        int d = c0 + ty + j;
        int s = r0 + tx;
        Atr[(size_t)d * NN + s] = tile[tx][ty + j] * dinv[d] * dinv[s];
    }
}

// ---------------------------------------------------------------------------
// K6: final transpose: out[(b*L+l)*N + d] = outn[d][b*L+l] + bias[l]
__global__ __launch_bounds__(256) void k_out_tr(const float* __restrict__ outn,
                                                const float* __restrict__ bias,
                                                float* __restrict__ out) {
    __shared__ float tile[32][33];
    int c0 = blockIdx.x * 32;   // r = b*L + l
    int r0 = blockIdx.y * 32;   // d
    int tx = threadIdx.x, ty = threadIdx.y;
#pragma unroll
    for (int j = 0; j < 32; j += 8)
        tile[ty + j][tx] = outn[(size_t)(r0 + ty + j) * BL + c0 + tx];
    __syncthreads();
#pragma unroll
    for (int j = 0; j < 32; j += 8) {
        int r = c0 + ty + j;
        int d = r0 + tx;
        out[(size_t)r * NN + d] = tile[tx][ty + j] + bias[r & (LL - 1)];
    }
}

// ---------------------------------------------------------------------------
extern "C" void kernel_launch(void* const* d_in, const int* in_sizes, int n_in,
                              void* d_out, int out_size, void* d_ws, size_t ws_size,
                              hipStream_t stream) {
    const float* x      = (const float*)d_in[0];   // [B, L, N]
    const float* weight = (const float*)d_in[1];   // [L, L]
    const float* bias   = (const float*)d_in[2];   // [L]
    float* out = (float*)d_out;                    // [B, L, N]

    // workspace layout (floats)
    float* ws   = (float*)d_ws;
    float* xs   = ws;                       // [N][B*L]  scaled (normalized) feats
    float* xnT  = xs   + (size_t)NN * BL;   // [N][B*L]  raw node-major feats
    float* sim  = xnT  + (size_t)NN * BL;   // [N][N]
    float* A    = sim  + (size_t)NN * NN;   // [N][N]    masked sim (row = src)
    float* Atr  = A    + (size_t)NN * NN;   // [N][N]    normalized, transposed
    float* dinv = Atr  + (size_t)NN * NN;   // [N]
    float* invn = dinv + NN;                // [B*N]
    float* xw   = invn + (size_t)BB * NN;   // [N][B*L]  transformed feats
    float* outn = xs;                       // reuse xs after GEMM1: [N][B*L]

    // 1. per-(n,b) inverse norms
    k_norms<<<dim3(BB * NN / 256), 256, 0, stream>>>(x, invn);
    // 2. transpose to node-major (+ scaled copy)
    k_transpose_x<<<dim3(NN / 32, BL / 32), dim3(32, 8), 0, stream>>>(x, invn, xnT, xs);
    // 3. mean_sim = xs . xs^T / B      [1024 x 1024 x 8192]
    k_sgemm_nt<<<dim3(NN / 64, NN / 64), 256, 0, stream>>>(xs, xs, sim,
                                                           NN, NN, BL, 1.0f / BB);
    // 4. exact top-307 per row -> A
    k_topk<<<dim3(NN), 256, 0, stream>>>(sim, A);
    // 5. degree + rsqrt
    k_deg<<<dim3(NN / 256), 256, 0, stream>>>(A, dinv);
    // 6. Atr = D^-1/2 A^T D^-1/2
    k_prescale_tr<<<dim3(NN / 32, NN / 32), dim3(32, 8), 0, stream>>>(A, dinv, Atr);
    // 7. xw = xn . W                   [32768 x 256 x 256]
    k_sgemm_nn<<<dim3(LL / 64, (NN * BB) / 64), 256, 0, stream>>>(xnT, weight, xw,
                                                                  NN * BB, LL, LL, 1.0f);
    // 8. outn = Atr . xw               [1024 x 8192 x 1024]
    k_sgemm_nn<<<dim3(BL / 64, NN / 64), 256, 0, stream>>>(Atr, xw, outn,
                                                           NN, BL, NN, 1.0f);
    // 9. transpose back + bias
    k_out_tr<<<dim3(BL / 32, NN / 32), dim3(32, 8), 0, stream>>>(outn, bias, out);
}

// Round 2
// 301.033 us; speedup vs baseline: 3.0269x; 3.0269x over previous
//
#include <hip/hip_runtime.h>

// Problem constants
#define BB 32
#define LL 256
#define NN 1024
#define BL 8192         // B*L
#define TOPK 307        // int(1024*0.3)

typedef unsigned short ushort_t;
typedef __bf16 bf16x8 __attribute__((ext_vector_type(8)));
typedef float f32x4 __attribute__((ext_vector_type(4)));

// round-to-nearest-even float -> bf16 (inputs are finite, no NaN handling)
__device__ __forceinline__ ushort_t f2bf(float f) {
    unsigned int u = __float_as_uint(f);
    u += 0x7FFFu + ((u >> 16) & 1u);
    return (ushort_t)(u >> 16);
}
__device__ __forceinline__ float bf2f(ushort_t h) {
    return __uint_as_float(((unsigned int)h) << 16);
}

// ---------------------------------------------------------------------------
// K1: inv_norm[b*N + n] = 1 / max(||x[b,:,n]||, 1e-12)
__global__ __launch_bounds__(256) void k_norms(const float* __restrict__ x,
                                               float* __restrict__ invn) {
    int g = blockIdx.x * 256 + threadIdx.x;   // g = b*N + n
    int b = g >> 10, n = g & (NN - 1);
    const float* p = x + (size_t)b * LL * NN + n;
    float s = 0.f;
#pragma unroll 8
    for (int l = 0; l < LL; ++l) {
        float v = p[(size_t)l * NN];
        s = fmaf(v, v, s);
    }
    invn[g] = 1.0f / fmaxf(sqrtf(s), 1e-12f);
}

// ---------------------------------------------------------------------------
// K2: transpose x [8192][1024] -> node-major bf16 matrices:
//     xhi/xlo = hi/lo split of normalized feats, xbf = raw feats (bf16)
__global__ __launch_bounds__(256) void k_transpose_x(const float* __restrict__ x,
                                                     const float* __restrict__ invn,
                                                     ushort_t* __restrict__ xhi,
                                                     ushort_t* __restrict__ xlo,
                                                     ushort_t* __restrict__ xbf) {
    __shared__ float tile[32][33];
    int c0 = blockIdx.x * 32;       // node dim
    int r0 = blockIdx.y * 32;       // b*L dim
    int tx = threadIdx.x, ty = threadIdx.y;   // (32,8)
#pragma unroll
    for (int j = 0; j < 32; j += 8)
        tile[ty + j][tx] = x[(size_t)(r0 + ty + j) * NN + c0 + tx];
    __syncthreads();
    int b = r0 >> 8;                // whole tile in same batch (32 | 256)
#pragma unroll
    for (int j = 0; j < 32; j += 8) {
        int n = c0 + ty + j;
        size_t o = (size_t)n * BL + r0 + tx;
        float v = tile[tx][ty + j];
        xbf[o] = f2bf(v);
        float s = v * invn[b * NN + n];
        ushort_t hi = f2bf(s);
        xhi[o] = hi;
        xlo[o] = f2bf(s - bf2f(hi));
    }
}

// ---------------------------------------------------------------------------
// GEMM1: sim += (1/B) * Xs . Xs^T  via split-bf16 MFMA (hi*hi + hi*lo + lo*hi)
// 128x128 tile, BK=32, 256 threads (4 waves, each 32 rows x 128 cols),
// split-K over blockIdx.z (8 chunks of 1024), fp32 atomicAdd epilogue.
__global__ __launch_bounds__(256) void k_sim_mfma(const ushort_t* __restrict__ Xhi,
                                                  const ushort_t* __restrict__ Xlo,
                                                  float* __restrict__ sim) {
    __shared__ ushort_t sAh[128 * 32], sAl[128 * 32];
    __shared__ ushort_t sBh[128 * 32], sBl[128 * 32];
    const int t = threadIdx.x, l = t & 63, w = t >> 6;
    const int i0 = blockIdx.y * 128, j0 = blockIdx.x * 128;
    const int kbase = blockIdx.z * (BL / 8);
    // staging chunks: chunk c covers LDS row c>>2, k-quad c&3 (8 bf16 = 16B)
    const int ca = t, cb = t + 256;
    const int ra = ca >> 2, qa = (ca & 3) * 8;
    const int rb = cb >> 2, qb = (cb & 3) * 8;
    f32x4 acc[2][8] = {};
    const int lrow = l & 15, lq = (l >> 4) * 8;
    for (int k0 = 0; k0 < BL / 8; k0 += 32) {
        const size_t ka = (size_t)(kbase + k0);
        uint4 ah0 = *(const uint4*)(Xhi + (size_t)(i0 + ra) * BL + ka + qa);
        uint4 ah1 = *(const uint4*)(Xhi + (size_t)(i0 + rb) * BL + ka + qb);
        uint4 al0 = *(const uint4*)(Xlo + (size_t)(i0 + ra) * BL + ka + qa);
        uint4 al1 = *(const uint4*)(Xlo + (size_t)(i0 + rb) * BL + ka + qb);
        uint4 bh0 = *(const uint4*)(Xhi + (size_t)(j0 + ra) * BL + ka + qa);
        uint4 bh1 = *(const uint4*)(Xhi + (size_t)(j0 + rb) * BL + ka + qb);
        uint4 bl0 = *(const uint4*)(Xlo + (size_t)(j0 + ra) * BL + ka + qa);
        uint4 bl1 = *(const uint4*)(Xlo + (size_t)(j0 + rb) * BL + ka + qb);
        __syncthreads();   // previous iter's LDS reads complete
        *(uint4*)&sAh[ca * 8] = ah0; *(uint4*)&sAh[cb * 8] = ah1;
        *(uint4*)&sAl[ca * 8] = al0; *(uint4*)&sAl[cb * 8] = al1;
        *(uint4*)&sBh[ca * 8] = bh0; *(uint4*)&sBh[cb * 8] = bh1;
        *(uint4*)&sBl[ca * 8] = bl0; *(uint4*)&sBl[cb * 8] = bl1;
        __syncthreads();   // writes visible
        bf16x8 ah[2], al[2];
        ah[0] = *(const bf16x8*)&sAh[(w * 32 + lrow) * 32 + lq];
        ah[1] = *(const bf16x8*)&sAh[(w * 32 + 16 + lrow) * 32 + lq];
        al[0] = *(const bf16x8*)&sAl[(w * 32 + lrow) * 32 + lq];
        al[1] = *(const bf16x8*)&sAl[(w * 32 + 16 + lrow) * 32 + lq];
#pragma unroll
        for (int c = 0; c < 8; ++c) {
            bf16x8 bh = *(const bf16x8*)&sBh[(c * 16 + lrow) * 32 + lq];
            bf16x8 bl = *(const bf16x8*)&sBl[(c * 16 + lrow) * 32 + lq];
#pragma unroll
            for (int r = 0; r < 2; ++r) {
                acc[r][c] = __builtin_amdgcn_mfma_f32_16x16x32_bf16(ah[r], bh, acc[r][c], 0, 0, 0);
                acc[r][c] = __builtin_amdgcn_mfma_f32_16x16x32_bf16(ah[r], bl, acc[r][c], 0, 0, 0);
                acc[r][c] = __builtin_amdgcn_mfma_f32_16x16x32_bf16(al[r], bh, acc[r][c], 0, 0, 0);
            }
        }
    }
    const int orow = i0 + w * 32 + (l >> 4) * 4;
    const int ocol = j0 + lrow;
#pragma unroll
    for (int r = 0; r < 2; ++r)
#pragma unroll
        for (int c = 0; c < 8; ++c)
#pragma unroll
            for (int p = 0; p < 4; ++p)
                atomicAdd(&sim[(size_t)(orow + r * 16 + p) * NN + ocol + c * 16],
                          acc[r][c][p] * (1.0f / BB));
}

// ---------------------------------------------------------------------------
// Generic plain-bf16 NT MFMA GEMM: C[i][j] = sum_k A[i][k]*B[j][k]
// 128x128 tile, BK=32, batched via blockIdx.z strides. bf16out selects C dtype.
__global__ __launch_bounds__(256) void k_mfma_nt(const ushort_t* __restrict__ A,
                                                 const ushort_t* __restrict__ B,
                                                 void* __restrict__ Cv,
                                                 int lda, int ldb, int ldc,
                                                 long strA, long strB, long strC,
                                                 int K, int bf16out) {
    __shared__ ushort_t sA[128 * 32], sB[128 * 32];
    const int t = threadIdx.x, l = t & 63, w = t >> 6;
    const int i0 = blockIdx.y * 128, j0 = blockIdx.x * 128, z = blockIdx.z;
    const ushort_t* Ab = A + (size_t)z * strA;
    const ushort_t* Bb = B + (size_t)z * strB;
    const int ca = t, cb = t + 256;
    const int ra = ca >> 2, qa = (ca & 3) * 8;
    const int rb = cb >> 2, qb = (cb & 3) * 8;
    f32x4 acc[2][8] = {};
    const int lrow = l & 15, lq = (l >> 4) * 8;
    for (int k0 = 0; k0 < K; k0 += 32) {
        uint4 a0 = *(const uint4*)(Ab + (size_t)(i0 + ra) * lda + k0 + qa);
        uint4 a1 = *(const uint4*)(Ab + (size_t)(i0 + rb) * lda + k0 + qb);
        uint4 b0 = *(const uint4*)(Bb + (size_t)(j0 + ra) * ldb + k0 + qa);
        uint4 b1 = *(const uint4*)(Bb + (size_t)(j0 + rb) * ldb + k0 + qb);
        __syncthreads();
        *(uint4*)&sA[ca * 8] = a0; *(uint4*)&sA[cb * 8] = a1;
        *(uint4*)&sB[ca * 8] = b0; *(uint4*)&sB[cb * 8] = b1;
        __syncthreads();
        bf16x8 af0 = *(const bf16x8*)&sA[(w * 32 + lrow) * 32 + lq];
        bf16x8 af1 = *(const bf16x8*)&sA[(w * 32 + 16 + lrow) * 32 + lq];
#pragma unroll
        for (int c = 0; c < 8; ++c) {
            bf16x8 bf = *(const bf16x8*)&sB[(c * 16 + lrow) * 32 + lq];
            acc[0][c] = __builtin_amdgcn_mfma_f32_16x16x32_bf16(af0, bf, acc[0][c], 0, 0, 0);
            acc[1][c] = __builtin_amdgcn_mfma_f32_16x16x32_bf16(af1, bf, acc[1][c], 0, 0, 0);
        }
    }
    const int orow = i0 + w * 32 + (l >> 4) * 4;
    const int ocol = j0 + lrow;
    if (bf16out) {
        ushort_t* Cp = (ushort_t*)Cv + (size_t)z * strC;
#pragma unroll
        for (int r = 0; r < 2; ++r)
#pragma unroll
            for (int c = 0; c < 8; ++c)
#pragma unroll
                for (int p = 0; p < 4; ++p)
                    Cp[(size_t)(orow + r * 16 + p) * ldc + ocol + c * 16] = f2bf(acc[r][c][p]);
    } else {
        float* Cp = (float*)Cv + (size_t)z * strC;
#pragma unroll
        for (int r = 0; r < 2; ++r)
#pragma unroll
            for (int c = 0; c < 8; ++c)
#pragma unroll
                for (int p = 0; p < 4; ++p)
                    Cp[(size_t)(orow + r * 16 + p) * ldc + ocol + c * 16] = acc[r][c][p];
    }
}

// ---------------------------------------------------------------------------
// K3: per-row exact top-307 (excluding self) via radix select on ordered keys.
__global__ __launch_bounds__(256) void k_topk(const float* __restrict__ sim,
                                              float* __restrict__ A) {
    __shared__ unsigned int key[NN];
    __shared__ unsigned int hist[256];
    __shared__ unsigned int s_prefix;
    __shared__ int s_rem;
    const int n = blockIdx.x;
    const int t = threadIdx.x;
    const float* row = sim + (size_t)n * NN;
#pragma unroll
    for (int m = t; m < NN; m += 256) {
        unsigned int u = __float_as_uint(row[m]);
        unsigned int kk = (u & 0x80000000u) ? ~u : (u | 0x80000000u);
        if (m == n) kk = 0u;    // exclude self (self-sim = 1.0 is always max)
        key[m] = kk;
    }
    if (t == 0) { s_rem = TOPK; s_prefix = 0u; }
    __syncthreads();
    unsigned int prefix = 0u;
    for (int pass = 0; pass < 4; ++pass) {
        const int shift = 24 - 8 * pass;
        hist[t] = 0u;
        __syncthreads();
        unsigned int himask = (pass == 0) ? 0u : (0xFFFFFFFFu << (shift + 8));
#pragma unroll
        for (int m = t; m < NN; m += 256) {
            unsigned int kk = key[m];
            if (((kk ^ prefix) & himask) == 0u)
                atomicAdd(&hist[(kk >> shift) & 255u], 1u);
        }
        __syncthreads();
        if (t == 0) {
            int rem = s_rem;
            int b;
            for (b = 255; b > 0; --b) {
                int c = (int)hist[b];
                if (rem <= c) break;
                rem -= c;
            }
            s_rem = rem;
            s_prefix = prefix | ((unsigned int)b << shift);
        }
        __syncthreads();
        prefix = s_prefix;
    }
    const unsigned int T = prefix;
    const int need = s_rem;
    const int cnt_eq = (int)hist[T & 255u];
    if (cnt_eq != need) {
        if (t == 0) {
            int c = 0;
            for (int m = 0; m < NN; ++m) {
                if (key[m] == T) {
                    ++c;
                    if (c > need) key[m] = 0u;
                }
            }
        }
        __syncthreads();
    }
#pragma unroll
    for (int m = t; m < NN; m += 256)
        A[(size_t)n * NN + m] = (key[m] >= T) ? row[m] : 0.0f;
}

// ---------------------------------------------------------------------------
// K4a: partial column sums of A -> atomicAdd into deg (deg pre-zeroed)
__global__ __launch_bounds__(256) void k_deg(const float* __restrict__ A,
                                             float* __restrict__ deg) {
    int d = blockIdx.x * 256 + threadIdx.x;
    int s0 = blockIdx.y * 128;
    float s = 0.f;
#pragma unroll 8
    for (int i = 0; i < 128; ++i) s += A[(size_t)(s0 + i) * NN + d];
    atomicAdd(&deg[d], s);
}
// K4b: dinv = deg>0 ? 1/sqrt(deg) : 0
__global__ __launch_bounds__(256) void k_dinv(const float* __restrict__ deg,
                                              float* __restrict__ dinv) {
    int d = blockIdx.x * 256 + threadIdx.x;
    float s = deg[d];
    dinv[d] = (s > 0.f) ? (1.0f / sqrtf(s)) : 0.0f;
}

// ---------------------------------------------------------------------------
// K5: Atr[d][s] = bf16( A[s][d] * dinv[d] * dinv[s] )
__global__ __launch_bounds__(256) void k_prescale_tr(const float* __restrict__ A,
                                                     const float* __restrict__ dinv,
                                                     ushort_t* __restrict__ Atr) {
    __shared__ float tile[32][33];
    int c0 = blockIdx.x * 32;   // d
    int r0 = blockIdx.y * 32;   // s
    int tx = threadIdx.x, ty = threadIdx.y;
#pragma unroll
    for (int j = 0; j < 32; j += 8)
        tile[ty + j][tx] = A[(size_t)(r0 + ty + j) * NN + c0 + tx];
    __syncthreads();
#pragma unroll
    for (int j = 0; j < 32; j += 8) {
        int d = c0 + ty + j;
        int s = r0 + tx;
        Atr[(size_t)d * NN + s] = f2bf(tile[tx][ty + j] * dinv[d] * dinv[s]);
    }
}

// ---------------------------------------------------------------------------
// K5b: WT[o][l] = bf16( W[l][o] )
__global__ __launch_bounds__(256) void k_wt(const float* __restrict__ W,
                                            ushort_t* __restrict__ WT) {
    __shared__ float tile[32][33];
    int c0 = blockIdx.x * 32;   // o
    int r0 = blockIdx.y * 32;   // l
    int tx = threadIdx.x, ty = threadIdx.y;
#pragma unroll
    for (int j = 0; j < 32; j += 8)
        tile[ty + j][tx] = W[(size_t)(r0 + ty + j) * LL + c0 + tx];
    __syncthreads();
#pragma unroll
    for (int j = 0; j < 32; j += 8)
        WT[(size_t)(c0 + ty + j) * LL + r0 + tx] = f2bf(tile[tx][ty + j]);
}

// ---------------------------------------------------------------------------
// K6: final transpose: out[(b*L+l)*N + d] = outn[d][b*L+l] + bias[l]
__global__ __launch_bounds__(256) void k_out_tr(const float* __restrict__ outn,
                                                const float* __restrict__ bias,
                                                float* __restrict__ out) {
    __shared__ float tile[32][33];
    int c0 = blockIdx.x * 32;   // r = b*L + l
    int r0 = blockIdx.y * 32;   // d
    int tx = threadIdx.x, ty = threadIdx.y;
#pragma unroll
    for (int j = 0; j < 32; j += 8)
        tile[ty + j][tx] = outn[(size_t)(r0 + ty + j) * BL + c0 + tx];
    __syncthreads();
#pragma unroll
    for (int j = 0; j < 32; j += 8) {
        int r = c0 + ty + j;
        int d = r0 + tx;
        out[(size_t)r * NN + d] = tile[tx][ty + j] + bias[r & (LL - 1)];
    }
}

// ---------------------------------------------------------------------------
extern "C" void kernel_launch(void* const* d_in, const int* in_sizes, int n_in,
                              void* d_out, int out_size, void* d_ws, size_t ws_size,
                              hipStream_t stream) {
    const float* x      = (const float*)d_in[0];   // [B, L, N]
    const float* weight = (const float*)d_in[1];   // [L, L]
    const float* bias   = (const float*)d_in[2];   // [L]
    float* out = (float*)d_out;                    // [B, L, N]

    // workspace carve (all block sizes 16B-multiples)
    char* p = (char*)d_ws;
    ushort_t* xhi  = (ushort_t*)p; p += (size_t)NN * BL * 2;   // 16MB
    ushort_t* xlo  = (ushort_t*)p; p += (size_t)NN * BL * 2;   // 16MB
    ushort_t* xbf  = (ushort_t*)p; p += (size_t)NN * BL * 2;   // 16MB
    ushort_t* xwT  = (ushort_t*)p; p += (size_t)BL * NN * 2;   // 16MB [bl][n]
    ushort_t* Atrb = (ushort_t*)p; p += (size_t)NN * NN * 2;   // 2MB
    ushort_t* WTb  = (ushort_t*)p; p += (size_t)LL * LL * 2;   // 128KB
    float* sim  = (float*)p; p += (size_t)NN * NN * 4;         // 4MB
    float* Aw   = (float*)p; p += (size_t)NN * NN * 4;         // 4MB
    float* outn = (float*)p; p += (size_t)NN * BL * 4;         // 32MB
    float* deg  = (float*)p; p += NN * 4;
    float* dinv = (float*)p; p += NN * 4;
    float* invn = (float*)p; p += (size_t)BB * NN * 4;         // 128KB

    // 1. per-(n,b) inverse norms
    k_norms<<<dim3(BB * NN / 256), 256, 0, stream>>>(x, invn);
    // 2. transpose to node-major bf16 (hi/lo normalized + raw)
    k_transpose_x<<<dim3(NN / 32, BL / 32), dim3(32, 8), 0, stream>>>(x, invn, xhi, xlo, xbf);
    // 3. sim = (1/B) xs.xs^T  (split-bf16 MFMA, split-K=8, atomic accumulate)
    hipMemsetAsync(sim, 0, (size_t)NN * NN * 4, stream);
    hipMemsetAsync(deg, 0, NN * 4, stream);
    k_sim_mfma<<<dim3(NN / 128, NN / 128, 8), 256, 0, stream>>>(xhi, xlo, sim);
    // 4. exact top-307 per row -> Aw
    k_topk<<<dim3(NN), 256, 0, stream>>>(sim, Aw);
    // 5. degree + rsqrt
    k_deg<<<dim3(NN / 256, 8), 256, 0, stream>>>(Aw, deg);
    k_dinv<<<dim3(NN / 256), 256, 0, stream>>>(deg, dinv);
    // 6. Atr = bf16(D^-1/2 A^T D^-1/2), WT = bf16(W^T)
    k_prescale_tr<<<dim3(NN / 32, NN / 32), dim3(32, 8), 0, stream>>>(Aw, dinv, Atrb);
    k_wt<<<dim3(LL / 32, LL / 32), dim3(32, 8), 0, stream>>>(weight, WTb);
    // 7. xwT[b*256+o][n] = sum_l WT[o][l] * xbf[n][b*256+l]  (batched NT, bf16 out)
    k_mfma_nt<<<dim3(NN / 128, LL / 128, BB), 256, 0, stream>>>(
        WTb, xbf, xwT, LL, BL, NN, 0, LL, (long)LL * NN, LL, 1);
    // 8. outn[d][bl] = sum_s Atr[d][s] * xwT[bl][s]  (NT, fp32 out)
    k_mfma_nt<<<dim3(BL / 128, NN / 128, 1), 256, 0, stream>>>(
        Atrb, xwT, outn, NN, NN, BL, 0, 0, 0, NN, 0);
    // 9. transpose back + bias
    k_out_tr<<<dim3(BL / 32, NN / 32), dim3(32, 8), 0, stream>>>(outn, bias, out);
}

// Round 3
// 251.555 us; speedup vs baseline: 3.6222x; 1.1967x over previous
//
#include <hip/hip_runtime.h>

// Problem constants
#define BB 32
#define LL 256
#define NN 1024
#define BL 8192         // B*L
#define TOPK 307        // int(1024*0.3)
#define SPLITK 14

typedef unsigned short ushort_t;
typedef unsigned long long u64;
typedef __bf16 bf16x8 __attribute__((ext_vector_type(8)));
typedef float f32x4 __attribute__((ext_vector_type(4)));

// round-to-nearest-even float -> bf16
__device__ __forceinline__ ushort_t f2bf(float f) {
    unsigned int u = __float_as_uint(f);
    u += 0x7FFFu + ((u >> 16) & 1u);
    return (ushort_t)(u >> 16);
}
__device__ __forceinline__ float bf2f(ushort_t h) {
    return __uint_as_float(((unsigned int)h) << 16);
}

// async global->LDS DMA, 16B per lane. LDS dest: wave-uniform base + lane*16.
// AS casts via integer round-trip (apertures are 4GiB-aligned: low 32 bits of a
// flat LDS address == LDS byte offset — same trick composable_kernel uses).
__device__ __forceinline__ void gload16(const void* g, const void* l) {
    __builtin_amdgcn_global_load_lds(
        (__attribute__((address_space(1))) void*)(unsigned long long)g,
        (__attribute__((address_space(3))) void*)(unsigned int)(unsigned long long)l,
        16, 0, 0);
}

// ---------------------------------------------------------------------------
// K1: inv_norm[b*N + n] = 1 / max(||x[b,:,n]||, 1e-12)
__global__ __launch_bounds__(256) void k_norms(const float* __restrict__ x,
                                               float* __restrict__ invn) {
    int g = blockIdx.x * 256 + threadIdx.x;   // g = b*N + n
    int b = g >> 10, n = g & (NN - 1);
    const float* p = x + (size_t)b * LL * NN + n;
    float s = 0.f;
#pragma unroll 8
    for (int l = 0; l < LL; ++l) {
        float v = p[(size_t)l * NN];
        s = fmaf(v, v, s);
    }
    invn[g] = 1.0f / fmaxf(sqrtf(s), 1e-12f);
}

// ---------------------------------------------------------------------------
// K2: transpose x [8192][1024] -> node-major bf16: xhi/xlo (normalized split), xbf (raw)
__global__ __launch_bounds__(256) void k_transpose_x(const float* __restrict__ x,
                                                     const float* __restrict__ invn,
                                                     ushort_t* __restrict__ xhi,
                                                     ushort_t* __restrict__ xlo,
                                                     ushort_t* __restrict__ xbf) {
    __shared__ float tile[32][33];
    int c0 = blockIdx.x * 32;       // node dim
    int r0 = blockIdx.y * 32;       // b*L dim
    int tx = threadIdx.x, ty = threadIdx.y;   // (32,8)
#pragma unroll
    for (int j = 0; j < 32; j += 8)
        tile[ty + j][tx] = x[(size_t)(r0 + ty + j) * NN + c0 + tx];
    __syncthreads();
    int b = r0 >> 8;                // whole tile in same batch (32 | 256)
#pragma unroll
    for (int j = 0; j < 32; j += 8) {
        int n = c0 + ty + j;
        size_t o = (size_t)n * BL + r0 + tx;
        float v = tile[tx][ty + j];
        xbf[o] = f2bf(v);
        float s = v * invn[b * NN + n];
        ushort_t hi = f2bf(s);
        xhi[o] = hi;
        xlo[o] = f2bf(s - bf2f(hi));
    }
}

// ---------------------------------------------------------------------------
// GEMM1: sim += (1/B) Xs.Xs^T, split-bf16 (hi*hi + hi*lo + lo*hi), MFMA.
// Upper-triangular 128-tiles only (36 of 64), splitK=14 w/ uneven chunks,
// m97-style: 2x2 waves, acc[4][4]/wave, global_load_lds staging.
__global__ __launch_bounds__(256, 2) void k_sim_mfma(const ushort_t* __restrict__ Xhi,
                                                     const ushort_t* __restrict__ Xlo,
                                                     float* __restrict__ sim) {
    __shared__ ushort_t sAh[128 * 32], sAl[128 * 32];
    __shared__ ushort_t sBh[128 * 32], sBl[128 * 32];
    const int t = threadIdx.x, l = t & 63, w = t >> 6;
    // map blockIdx.x in [0,36) -> upper-tri tile (ti, tj), tj >= ti
    int id = blockIdx.x, ti = 0;
    while (id >= 8 - ti) { id -= 8 - ti; ++ti; }
    const int tj = ti + id;
    const int i0 = ti * 128, j0 = tj * 128;
    const int z = blockIdx.y;
    const int it0 = (256 * z) / SPLITK, it1 = (256 * (z + 1)) / SPLITK;
    // staging: chunk c covers LDS row c>>2, k-quad c&3; thread t owns c=t, c=t+256
    const int ra = t >> 2, qa = (t & 3) * 8;
    const int rb = (t + 256) >> 2, qb = ((t + 256) & 3) * 8;
    const int lb0 = 512 * w, lb1 = 512 * (w + 4);   // wave-uniform LDS bases (elems)
    const int wr = (w >> 1) * 64, wc = (w & 1) * 64;
    const int lrow = l & 15, lq = (l >> 4) * 8;
    const ushort_t* Ah = Xhi + (size_t)i0 * BL;
    const ushort_t* Al = Xlo + (size_t)i0 * BL;
    const ushort_t* Bh = Xhi + (size_t)j0 * BL;
    const ushort_t* Bl = Xlo + (size_t)j0 * BL;
    f32x4 acc[4][4] = {};
    for (int it = it0; it < it1; ++it) {
        const int k0 = it * 32;
        __syncthreads();   // prior iter's LDS reads done
        gload16(Ah + (size_t)ra * BL + k0 + qa, sAh + lb0);
        gload16(Ah + (size_t)rb * BL + k0 + qb, sAh + lb1);
        gload16(Al + (size_t)ra * BL + k0 + qa, sAl + lb0);
        gload16(Al + (size_t)rb * BL + k0 + qb, sAl + lb1);
        gload16(Bh + (size_t)ra * BL + k0 + qa, sBh + lb0);
        gload16(Bh + (size_t)rb * BL + k0 + qb, sBh + lb1);
        gload16(Bl + (size_t)ra * BL + k0 + qa, sBl + lb0);
        gload16(Bl + (size_t)rb * BL + k0 + qb, sBl + lb1);
        __syncthreads();   // DMA drained (vmcnt(0) before barrier)
        bf16x8 ah[4], al[4], bh[4], bl[4];
#pragma unroll
        for (int r = 0; r < 4; ++r) {
            ah[r] = *(const bf16x8*)&sAh[(wr + r * 16 + lrow) * 32 + lq];
            al[r] = *(const bf16x8*)&sAl[(wr + r * 16 + lrow) * 32 + lq];
        }
#pragma unroll
        for (int c = 0; c < 4; ++c) {
            bh[c] = *(const bf16x8*)&sBh[(wc + c * 16 + lrow) * 32 + lq];
            bl[c] = *(const bf16x8*)&sBl[(wc + c * 16 + lrow) * 32 + lq];
        }
#pragma unroll
        for (int r = 0; r < 4; ++r)
#pragma unroll
            for (int c = 0; c < 4; ++c) {
                acc[r][c] = __builtin_amdgcn_mfma_f32_16x16x32_bf16(ah[r], bh[c], acc[r][c], 0, 0, 0);
                acc[r][c] = __builtin_amdgcn_mfma_f32_16x16x32_bf16(ah[r], bl[c], acc[r][c], 0, 0, 0);
                acc[r][c] = __builtin_amdgcn_mfma_f32_16x16x32_bf16(al[r], bh[c], acc[r][c], 0, 0, 0);
            }
    }
    const int orow = i0 + wr + (l >> 4) * 4;
    const int ocol = j0 + wc + lrow;
#pragma unroll
    for (int r = 0; r < 4; ++r)
#pragma unroll
        for (int c = 0; c < 4; ++c)
#pragma unroll
            for (int p = 0; p < 4; ++p)
                atomicAdd(&sim[(size_t)(orow + r * 16 + p) * NN + ocol + c * 16],
                          acc[r][c][p] * (1.0f / BB));
}

// ---------------------------------------------------------------------------
// Mirror strictly-lower 128-tiles from upper: sim[i][j] = sim[j][i]
__global__ __launch_bounds__(256) void k_mirror(float* __restrict__ sim) {
    __shared__ float tile[32][33];
    int c0 = blockIdx.x * 32;   // output col (j)
    int r0 = blockIdx.y * 32;   // output row (i)
    if ((r0 >> 7) <= (c0 >> 7)) return;   // only strictly-lower 128-tiles
    int tx = threadIdx.x, ty = threadIdx.y;
#pragma unroll
    for (int j = 0; j < 32; j += 8)
        tile[ty + j][tx] = sim[(size_t)(c0 + ty + j) * NN + r0 + tx];
    __syncthreads();
#pragma unroll
    for (int j = 0; j < 32; j += 8)
        sim[(size_t)(r0 + ty + j) * NN + c0 + tx] = tile[tx][ty + j];
}

// ---------------------------------------------------------------------------
// K3: exact top-307 per row (excl self). One wave per row; 16 keys/lane in
// registers; ballot-based binary search on order-transformed uint keys; exact
// tie handling (keep lowest indices) via ballot prefix ranks. No LDS, no syncs.
__global__ __launch_bounds__(256) void k_topk(const float* __restrict__ sim,
                                              float* __restrict__ A) {
    const int t = threadIdx.x, l = t & 63, w = t >> 6;
    const int n = blockIdx.x * 4 + w;
    const float* row = sim + (size_t)n * NN;
    float v[16]; unsigned key[16];
#pragma unroll
    for (int j = 0; j < 16; ++j) {
        int m = j * 64 + l;
        float f = row[m];
        v[j] = f;
        unsigned u = __float_as_uint(f);
        unsigned kk = (u & 0x80000000u) ? ~u : (u | 0x80000000u);
        key[j] = (m == n) ? 0u : kk;   // self excluded (self-sim is row max)
    }
    unsigned cur = 0u;
    for (int bit = 31; bit >= 0; --bit) {
        unsigned cand = cur | (1u << bit);
        int c = 0;
#pragma unroll
        for (int j = 0; j < 16; ++j)
            c += __popcll(__ballot(key[j] >= cand));
        if (c >= TOPK) cur = cand;     // uniform across wave
    }
    const unsigned T = cur;            // exact 307th-largest key
    int cgt = 0; u64 eq[16];
#pragma unroll
    for (int j = 0; j < 16; ++j) {
        cgt += __popcll(__ballot(key[j] > T));
        eq[j] = __ballot(key[j] == T);
    }
    const int need = TOPK - cgt;       // >= 1
    const u64 mymask = (l == 0) ? 0ull : (~0ull >> (64 - l));
    int base = 0;
#pragma unroll
    for (int j = 0; j < 16; ++j) {
        int rank = base + __popcll(eq[j] & mymask);
        bool keep = (key[j] > T) | ((key[j] == T) & (rank < need));
        A[(size_t)n * NN + j * 64 + l] = keep ? v[j] : 0.0f;
        base += __popcll(eq[j]);
    }
}

// ---------------------------------------------------------------------------
// K4a: partial column sums of A -> atomicAdd into deg (deg pre-zeroed)
__global__ __launch_bounds__(256) void k_deg(const float* __restrict__ A,
                                             float* __restrict__ deg) {
    int d = blockIdx.x * 256 + threadIdx.x;
    int s0 = blockIdx.y * 32;
    float s = 0.f;
#pragma unroll 8
    for (int i = 0; i < 32; ++i) s += A[(size_t)(s0 + i) * NN + d];
    atomicAdd(&deg[d], s);
}
// K4b: dinv = deg>0 ? 1/sqrt(deg) : 0
__global__ __launch_bounds__(256) void k_dinv(const float* __restrict__ deg,
                                              float* __restrict__ dinv) {
    int d = blockIdx.x * 256 + threadIdx.x;
    float s = deg[d];
    dinv[d] = (s > 0.f) ? (1.0f / sqrtf(s)) : 0.0f;
}

// ---------------------------------------------------------------------------
// K5: Atr[d][s] = bf16( A[s][d] * dinv[d] * dinv[s] )
__global__ __launch_bounds__(256) void k_prescale_tr(const float* __restrict__ A,
                                                     const float* __restrict__ dinv,
                                                     ushort_t* __restrict__ Atr) {
    __shared__ float tile[32][33];
    int c0 = blockIdx.x * 32;   // d
    int r0 = blockIdx.y * 32;   // s
    int tx = threadIdx.x, ty = threadIdx.y;
#pragma unroll
    for (int j = 0; j < 32; j += 8)
        tile[ty + j][tx] = A[(size_t)(r0 + ty + j) * NN + c0 + tx];
    __syncthreads();
#pragma unroll
    for (int j = 0; j < 32; j += 8) {
        int d = c0 + ty + j;
        int s = r0 + tx;
        Atr[(size_t)d * NN + s] = f2bf(tile[tx][ty + j] * dinv[d] * dinv[s]);
    }
}

// ---------------------------------------------------------------------------
// K5b: WT[o][l] = bf16( W[l][o] )
__global__ __launch_bounds__(256) void k_wt(const float* __restrict__ W,
                                            ushort_t* __restrict__ WT) {
    __shared__ float tile[32][33];
    int c0 = blockIdx.x * 32;   // o
    int r0 = blockIdx.y * 32;   // l
    int tx = threadIdx.x, ty = threadIdx.y;
#pragma unroll
    for (int j = 0; j < 32; j += 8)
        tile[ty + j][tx] = W[(size_t)(r0 + ty + j) * LL + c0 + tx];
    __syncthreads();
#pragma unroll
    for (int j = 0; j < 32; j += 8)
        WT[(size_t)(c0 + ty + j) * LL + r0 + tx] = f2bf(tile[tx][ty + j]);
}

// ---------------------------------------------------------------------------
// Generic bf16 NT MFMA GEMM (m97 structure): C[i][j] = sum_k A[i][k]*B[j][k].
// 128x128 tile, BK=32, 2x2 waves acc[4][4], global_load_lds staging, batched
// via blockIdx.z. fp32-out path fuses +bias[i & 255].
__global__ __launch_bounds__(256, 2) void k_mfma_nt(const ushort_t* __restrict__ A,
                                                    const ushort_t* __restrict__ B,
                                                    void* __restrict__ Cv,
                                                    const float* __restrict__ bias,
                                                    int lda, int ldb, int ldc,
                                                    long strA, long strB, long strC,
                                                    int K, int bf16out) {
    __shared__ ushort_t sA[128 * 32], sB[128 * 32];
    const int t = threadIdx.x, l = t & 63, w = t >> 6;
    const int i0 = blockIdx.y * 128, j0 = blockIdx.x * 128, z = blockIdx.z;
    const ushort_t* Ab = A + (size_t)z * strA;
    const ushort_t* Bb = B + (size_t)z * strB;
    const int ra = t >> 2, qa = (t & 3) * 8;
    const int rb = (t + 256) >> 2, qb = ((t + 256) & 3) * 8;
    const int lb0 = 512 * w, lb1 = 512 * (w + 4);
    const int wr = (w >> 1) * 64, wc = (w & 1) * 64;
    const int lrow = l & 15, lq = (l >> 4) * 8;
    f32x4 acc[4][4] = {};
    for (int k0 = 0; k0 < K; k0 += 32) {
        __syncthreads();
        gload16(Ab + (size_t)(i0 + ra) * lda + k0 + qa, sA + lb0);
        gload16(Ab + (size_t)(i0 + rb) * lda + k0 + qb, sA + lb1);
        gload16(Bb + (size_t)(j0 + ra) * ldb + k0 + qa, sB + lb0);
        gload16(Bb + (size_t)(j0 + rb) * ldb + k0 + qb, sB + lb1);
        __syncthreads();
        bf16x8 af[4], bf_[4];
#pragma unroll
        for (int r = 0; r < 4; ++r)
            af[r] = *(const bf16x8*)&sA[(wr + r * 16 + lrow) * 32 + lq];
#pragma unroll
        for (int c = 0; c < 4; ++c)
            bf_[c] = *(const bf16x8*)&sB[(wc + c * 16 + lrow) * 32 + lq];
#pragma unroll
        for (int r = 0; r < 4; ++r)
#pragma unroll
            for (int c = 0; c < 4; ++c)
                acc[r][c] = __builtin_amdgcn_mfma_f32_16x16x32_bf16(af[r], bf_[c], acc[r][c], 0, 0, 0);
    }
    const int orow = i0 + wr + (l >> 4) * 4;
    const int ocol = j0 + wc + lrow;
    if (bf16out) {
        ushort_t* Cp = (ushort_t*)Cv + (size_t)z * strC;
#pragma unroll
        for (int r = 0; r < 4; ++r)
#pragma unroll
            for (int c = 0; c < 4; ++c)
#pragma unroll
                for (int p = 0; p < 4; ++p)
                    Cp[(size_t)(orow + r * 16 + p) * ldc + ocol + c * 16] = f2bf(acc[r][c][p]);
    } else {
        float* Cp = (float*)Cv + (size_t)z * strC;
#pragma unroll
        for (int r = 0; r < 4; ++r)
#pragma unroll
            for (int c = 0; c < 4; ++c)
#pragma unroll
                for (int p = 0; p < 4; ++p) {
                    float bv = bias ? bias[(orow + r * 16 + p) & (LL - 1)] : 0.0f;
                    Cp[(size_t)(orow + r * 16 + p) * ldc + ocol + c * 16] = acc[r][c][p] + bv;
                }
    }
}

// ---------------------------------------------------------------------------
extern "C" void kernel_launch(void* const* d_in, const int* in_sizes, int n_in,
                              void* d_out, int out_size, void* d_ws, size_t ws_size,
                              hipStream_t stream) {
    const float* x      = (const float*)d_in[0];   // [B, L, N]
    const float* weight = (const float*)d_in[1];   // [L, L]
    const float* bias   = (const float*)d_in[2];   // [L]
    float* out = (float*)d_out;                    // [B, L, N] == [bl][d]

    char* p = (char*)d_ws;
    ushort_t* xhi  = (ushort_t*)p; p += (size_t)NN * BL * 2;   // 16MB
    ushort_t* xlo  = (ushort_t*)p; p += (size_t)NN * BL * 2;   // 16MB
    ushort_t* xbf  = (ushort_t*)p; p += (size_t)NN * BL * 2;   // 16MB
    ushort_t* xwT  = (ushort_t*)p; p += (size_t)BL * NN * 2;   // 16MB [bl][n]
    ushort_t* Atrb = (ushort_t*)p; p += (size_t)NN * NN * 2;   // 2MB
    ushort_t* WTb  = (ushort_t*)p; p += (size_t)LL * LL * 2;   // 128KB
    float* sim  = (float*)p; p += (size_t)NN * NN * 4;         // 4MB
    float* Aw   = (float*)p; p += (size_t)NN * NN * 4;         // 4MB
    float* deg  = (float*)p; p += NN * 4;
    float* dinv = (float*)p; p += NN * 4;
    float* invn = (float*)p; p += (size_t)BB * NN * 4;         // 128KB

    // 1. per-(n,b) inverse norms
    k_norms<<<dim3(BB * NN / 256), 256, 0, stream>>>(x, invn);
    // 2. transpose to node-major bf16 (hi/lo normalized + raw)
    k_transpose_x<<<dim3(NN / 32, BL / 32), dim3(32, 8), 0, stream>>>(x, invn, xhi, xlo, xbf);
    // 3. sim upper-tri (split-bf16 MFMA, splitK=14, atomics), then mirror
    hipMemsetAsync(sim, 0, (size_t)NN * NN * 4, stream);
    hipMemsetAsync(deg, 0, NN * 4, stream);
    k_sim_mfma<<<dim3(36, SPLITK), 256, 0, stream>>>(xhi, xlo, sim);
    k_mirror<<<dim3(NN / 32, NN / 32), dim3(32, 8), 0, stream>>>(sim);
    // 4. exact top-307 per row -> Aw
    k_topk<<<dim3(NN / 4), 256, 0, stream>>>(sim, Aw);
    // 5. degree + rsqrt
    k_deg<<<dim3(NN / 256, NN / 32), 256, 0, stream>>>(Aw, deg);
    k_dinv<<<dim3(NN / 256), 256, 0, stream>>>(deg, dinv);
    // 6. Atr = bf16(D^-1/2 A^T D^-1/2), WT = bf16(W^T)
    k_prescale_tr<<<dim3(NN / 32, NN / 32), dim3(32, 8), 0, stream>>>(Aw, dinv, Atrb);
    k_wt<<<dim3(LL / 32, LL / 32), dim3(32, 8), 0, stream>>>(weight, WTb);
    // 7. xwT[b*256+o][n] = sum_l WT[o][l] * xbf[n][b*256+l]  (batched NT, bf16 out)
    k_mfma_nt<<<dim3(NN / 128, LL / 128, BB), 256, 0, stream>>>(
        WTb, xbf, xwT, nullptr, LL, BL, NN, 0, LL, (long)LL * NN, LL, 1);
    // 8. out[bl][d] = sum_s xwT[bl][s] * Atr[d][s] + bias[bl&255]  (NT, fused epilogue)
    k_mfma_nt<<<dim3(NN / 128, BL / 128, 1), 256, 0, stream>>>(
        xwT, Atrb, out, bias, NN, NN, NN, 0, 0, 0, NN, 0);
}